// Round 11
// baseline (959.862 us; speedup 1.0000x reference)
//
#include <hip/hip_runtime.h>
#include <hip/hip_bf16.h>
#include <math.h>

#define NQ 4096
#define CC 256
#define GRID 768

typedef __attribute__((ext_vector_type(8))) short bfrag;
typedef __attribute__((ext_vector_type(4))) float ffrag;

__device__ inline unsigned short f2bf(float x) {
  __hip_bfloat16 h = __float2bfloat16(x);
  return *reinterpret_cast<unsigned short*>(&h);
}

__device__ inline float bf2f(unsigned short u) {
  return __uint_as_float(((unsigned)u) << 16);
}

__device__ inline void gload16(const void* g, void* l) {
  __builtin_amdgcn_global_load_lds(
      (const __attribute__((address_space(1))) void*)g,
      (__attribute__((address_space(3))) void*)l, 16, 0, 0);
}

// ================================================================= params
struct MP {
  const float *S, *f0, *f1, *f2, *sim;
  const float *vw0, *vb0, *vw1, *vb1, *vw2, *vb2;
  const float *q_w, *q_b, *off_w, *off_b, *wgt_w, *wgt_b, *out_w, *out_b;
  const float *lnq_g, *lnq_b, *lno_g, *lno_b;
  const float *fc1_w, *fc1_b, *fc2_w, *fc2_b;
  float *offwgt, *bias144, *Pp, *Vp1, *Vp2, *outp;
  unsigned short *Sbf, *Qbf, *accbf, *V0b, *V1b, *V2b;
  unsigned short *q_wb, *owb, *vw0b, *vw1b, *vw2b, *out_wb, *fc1_wb, *fc2_wb;
  unsigned *bars;
};

// ================================================================= grid bar
// Single-use counter per barrier. All GRID blocks are co-resident
// (LDS 40960B -> 4 blk/CU; __launch_bounds__(256,3) -> >=3 blk/CU; 3*256=768).
__device__ inline void gbar(unsigned* bars, int i) {
  __syncthreads();
  if (threadIdx.x == 0) {
    unsigned* slot = bars + i * 16;          // 64B apart
    __threadfence();                          // release my writes (device scope)
    atomicAdd(slot, 1u);
    while (atomicAdd(slot, 0u) < GRID) __builtin_amdgcn_s_sleep(8);
    __threadfence();                          // acquire others' writes
  }
  __syncthreads();
}

// ================================================================= GEMM body
// BK=64 k-major LDS. EPI 0: fp32+bias  1: GELU->bf16  2: +bias+bf16 Zres,
// transposed fp32 store  3: bf16+bias  4: fp32 no bias (partial)
template<int BM, int BN, int WM, int WN, int EPI>
__device__ __forceinline__ void gemm_body(
    const unsigned short* __restrict__ A, const unsigned short* __restrict__ B,
    const float* __restrict__ bias, float* __restrict__ outf,
    unsigned short* __restrict__ outb, int N, int Kloop, int lda, int ldb,
    int ldo, const unsigned short* __restrict__ Zres, float* __restrict__ outT,
    int m0, int n0, unsigned short* As, unsigned short* Bs) {
  constexpr int MI = BM / (WM * 16), NI = BN / (WN * 16);
  constexpr int TA = BM / 8, TB = BN / 8;
  constexpr int LBM = (BM == 32) ? 5 : (BM == 64) ? 6 : 7;
  constexpr int LBN = (BN == 64) ? 6 : (BN == 128) ? 7 : 8;
  int tid = threadIdx.x, wave = tid >> 6, lane = tid & 63;
  int quad = lane >> 4, l16 = lane & 15;
  int wm = wave / WN, wn = wave % WN;
  const int mbase = wm * (BM / WM), nbase = wn * (BN / WN);

  ffrag acc[MI][NI];
  #pragma unroll
  for (int i = 0; i < MI; i++)
    #pragma unroll
    for (int j = 0; j < NI; j++) acc[i][j] = (ffrag)0.f;

  for (int k0 = 0; k0 < Kloop; k0 += 64) {
    __syncthreads();
    for (int t = wave; t < TA + TB; t += 4) {
      if (t < TA) {
        int s = t * 64 + lane;
        int kc = s >> LBM, r = s & (BM - 1);
        gload16(A + (size_t)(m0 + r) * lda + k0 + kc * 8, (char*)As + t * 1024);
      } else {
        int s = (t - TA) * 64 + lane;
        int kc = s >> LBN, r = s & (BN - 1);
        gload16(B + (size_t)(n0 + r) * ldb + k0 + kc * 8, (char*)Bs + (t - TA) * 1024);
      }
    }
    __syncthreads();
    #pragma unroll
    for (int ks = 0; ks < 2; ks++) {
      bfrag af[MI], bf[NI];
      #pragma unroll
      for (int mi = 0; mi < MI; mi++)
        af[mi] = *(const bfrag*)(As + ((((ks * 4 + quad) << LBM) + mbase + mi * 16 + l16) << 3));
      #pragma unroll
      for (int ni = 0; ni < NI; ni++)
        bf[ni] = *(const bfrag*)(Bs + ((((ks * 4 + quad) << LBN) + nbase + ni * 16 + l16) << 3));
      #pragma unroll
      for (int mi = 0; mi < MI; mi++)
        #pragma unroll
        for (int ni = 0; ni < NI; ni++)
          acc[mi][ni] = __builtin_amdgcn_mfma_f32_16x16x32_bf16(
              af[mi], bf[ni], acc[mi][ni], 0, 0, 0);
    }
  }

  if (EPI == 2) {
    #pragma unroll
    for (int mi = 0; mi < MI; mi++) {
      int mrow = m0 + mbase + mi * 16 + quad * 4;
      int bb = mrow >> 12, q0 = mrow & (NQ - 1);
      #pragma unroll
      for (int ni = 0; ni < NI; ni++) {
        int n = n0 + nbase + ni * 16 + l16;
        float bv = bias[n];
        float4 v;
        v.x = acc[mi][ni][0] + bv + bf2f(Zres[(size_t)(mrow + 0) * CC + n]);
        v.y = acc[mi][ni][1] + bv + bf2f(Zres[(size_t)(mrow + 1) * CC + n]);
        v.z = acc[mi][ni][2] + bv + bf2f(Zres[(size_t)(mrow + 2) * CC + n]);
        v.w = acc[mi][ni][3] + bv + bf2f(Zres[(size_t)(mrow + 3) * CC + n]);
        *(float4*)(outT + ((size_t)(bb * CC + n)) * NQ + q0) = v;
      }
    }
  } else {
    #pragma unroll
    for (int mi = 0; mi < MI; mi++) {
      int mrow = m0 + mbase + mi * 16 + quad * 4;
      #pragma unroll
      for (int ni = 0; ni < NI; ni++) {
        int n = n0 + nbase + ni * 16 + l16;
        if (n < N) {
          float bv = (EPI == 4) ? 0.f : bias[n];
          #pragma unroll
          for (int r = 0; r < 4; r++) {
            float v = acc[mi][ni][r] + bv;
            if (EPI == 1) {
              v = 0.5f * v * (1.f + erff(v * 0.70710678118654752f));
              outb[(size_t)(mrow + r) * ldo + n] = f2bf(v);
            } else if (EPI == 3) {
              outb[(size_t)(mrow + r) * ldo + n] = f2bf(v);
            } else {
              outf[(size_t)(mrow + r) * ldo + n] = v;
            }
          }
        }
      }
    }
  }
}

// ================================================================= prep
__device__ void tr64(const float* __restrict__ src,
                     unsigned short* __restrict__ dstb, int Cin, int P,
                     int p0, int c0, int b, float (*t)[73]) {
  int tid = threadIdx.x;
  int rx = tid & 15, ry = tid >> 4;
  const float* Sb = src + (size_t)b * Cin * P + p0 + rx * 4;
  #pragma unroll
  for (int i = 0; i < 4; i++) {
    int r = ry + i * 16;
    float4 v = *(const float4*)(Sb + (size_t)(c0 + r) * P);
    t[r][rx * 4 + 0] = v.x; t[r][rx * 4 + 1] = v.y;
    t[r][rx * 4 + 2] = v.z; t[r][rx * 4 + 3] = v.w;
  }
  __syncthreads();
  size_t ob = (size_t)b * P * Cin;
  #pragma unroll
  for (int i = 0; i < 4; i++) {
    int pr = ry + i * 16;
    float x0 = t[rx * 4 + 0][pr], x1 = t[rx * 4 + 1][pr];
    float x2 = t[rx * 4 + 2][pr], x3 = t[rx * 4 + 3][pr];
    size_t idx = ob + (size_t)(p0 + pr) * Cin + c0 + rx * 4;
    ushort4 u4;
    u4.x = f2bf(x0); u4.y = f2bf(x1); u4.z = f2bf(x2); u4.w = f2bf(x3);
    *(ushort4*)(dstb + idx) = u4;
  }
}

static __device__ void prep_item(const MP& p, int bid, char* sm) {
  __syncthreads();               // guard LDS vs previous iteration readers
  float (*t)[73] = (float(*)[73])sm;
  if (bid < 512) {
    int l = bid;
    tr64(p.S, p.Sbf, 256, 4096, (l & 63) * 64, ((l >> 6) & 3) * 64, l >> 8, t);
  } else if (bid < 1024) {
    int l = bid - 512;
    tr64(p.f0, p.accbf, 256, 4096, (l & 63) * 64, ((l >> 6) & 3) * 64, l >> 8, t);
  } else if (bid < 1280) {
    int l = bid - 1024;
    tr64(p.f1, p.accbf + 2097152, 512, 1024, (l & 15) * 64, ((l >> 4) & 7) * 64, l >> 7, t);
  } else if (bid < 1408) {
    int l = bid - 1280;
    tr64(p.f2, p.accbf + 3145728, 1024, 256, (l & 3) * 64, ((l >> 2) & 15) * 64, l >> 6, t);
  } else if (bid < 2688) {
    int i4 = (bid - 1408) * 256 + threadIdx.x;
    const float* src; unsigned short* dst;
    if (i4 < 16384)       { src = p.q_w;   dst = p.q_wb; }
    else if (i4 < 32768)  { i4 -= 16384;  src = p.vw0;   dst = p.vw0b; }
    else if (i4 < 65536)  { i4 -= 32768;  src = p.vw1;   dst = p.vw1b; }
    else if (i4 < 131072) { i4 -= 65536;  src = p.vw2;   dst = p.vw2b; }
    else if (i4 < 196608) { i4 -= 131072; src = p.out_w; dst = p.out_wb; }
    else if (i4 < 262144) { i4 -= 196608; src = p.fc1_w; dst = p.fc1_wb; }
    else                  { i4 -= 262144; src = p.fc2_w; dst = p.fc2_wb; }
    float4 v = ((const float4*)src)[i4];
    ushort4 u; u.x = f2bf(v.x); u.y = f2bf(v.y); u.z = f2bf(v.z); u.w = f2bf(v.w);
    ((ushort4*)dst)[i4] = u;
  } else {
    int e = (bid - 2688) * 256 + threadIdx.x;
    float v = (e < 24576) ? p.off_w[e] : (e < 36864 ? p.wgt_w[e - 24576] : 0.f);
    p.owb[e] = f2bf(v);
    if (e < 96) p.bias144[e] = p.off_b[e];
    else if (e < 144) p.bias144[e] = p.wgt_b[e - 96];
  }
}

// ================================================================= Q GEMM+LN
static __device__ void gemm_ln_q(
    const unsigned short* __restrict__ A, const unsigned short* __restrict__ B,
    const float* __restrict__ bias, unsigned short* __restrict__ outb,
    const float* __restrict__ g, const float* __restrict__ be,
    int m0, char* sm) {
  unsigned short* As = (unsigned short*)sm;
  unsigned short* Bs = (unsigned short*)(sm + 4096);
  float* L = (float*)sm;
  const int K = 256;

  int tid = threadIdx.x, wave = tid >> 6, lane = tid & 63;
  int quad = lane >> 4, l16 = lane & 15;

  ffrag acc[2][4];
  #pragma unroll
  for (int i = 0; i < 2; i++)
    #pragma unroll
    for (int j = 0; j < 4; j++) acc[i][j] = (ffrag)0.f;

  for (int k0 = 0; k0 < K; k0 += 64) {
    __syncthreads();
    for (int t = wave; t < 36; t += 4) {
      if (t < 4) {
        int s = t * 64 + lane;
        int kc = s >> 5, r = s & 31;
        gload16(A + (size_t)(m0 + r) * K + k0 + kc * 8, sm + t * 1024);
      } else {
        int s = (t - 4) * 64 + lane;
        int kc = s >> 8, r = s & 255;
        gload16(B + (size_t)r * K + k0 + kc * 8, sm + 4096 + (t - 4) * 1024);
      }
    }
    __syncthreads();
    #pragma unroll
    for (int ks = 0; ks < 2; ks++) {
      bfrag af[2], bf[4];
      #pragma unroll
      for (int mi = 0; mi < 2; mi++)
        af[mi] = *(const bfrag*)(As + ((((ks * 4 + quad) << 5) + mi * 16 + l16) << 3));
      #pragma unroll
      for (int ni = 0; ni < 4; ni++)
        bf[ni] = *(const bfrag*)(Bs + ((((ks * 4 + quad) << 8) + wave * 64 + ni * 16 + l16) << 3));
      #pragma unroll
      for (int mi = 0; mi < 2; mi++)
        #pragma unroll
        for (int ni = 0; ni < 4; ni++)
          acc[mi][ni] = __builtin_amdgcn_mfma_f32_16x16x32_bf16(
              af[mi], bf[ni], acc[mi][ni], 0, 0, 0);
    }
  }
  __syncthreads();

  #pragma unroll
  for (int mi = 0; mi < 2; mi++) {
    int row = mi * 16 + quad * 4;
    #pragma unroll
    for (int ni = 0; ni < 4; ni++) {
      int col = wave * 64 + ni * 16 + l16;
      float bv = bias[col];
      #pragma unroll
      for (int r = 0; r < 4; r++)
        L[(row + r) * 264 + col] = acc[mi][ni][r] + bv;
    }
  }
  __syncthreads();

  int row = tid >> 3, j = tid & 7;
  int seg = ((j + row) & 7) * 32;
  const float* Lr = L + row * 264 + seg;
  float s1 = 0.f, s2 = 0.f;
  #pragma unroll
  for (int i = 0; i < 8; i++) {
    float4 t4 = *(const float4*)(Lr + i * 4);
    s1 += t4.x + t4.y + t4.z + t4.w;
    s2 += t4.x * t4.x + t4.y * t4.y + t4.z * t4.z + t4.w * t4.w;
  }
  #pragma unroll
  for (int o = 1; o < 8; o <<= 1) {
    s1 += __shfl_xor(s1, o);
    s2 += __shfl_xor(s2, o);
  }
  float mu = s1 * (1.f / 256.f);
  float var = s2 * (1.f / 256.f) - mu * mu;
  float rs = rsqrtf(var + 1e-5f);
  int gm = m0 + row;
  #pragma unroll
  for (int i = 0; i < 8; i++) {
    int col = seg + i * 4;
    float4 t4 = *(const float4*)(Lr + i * 4);
    float4 gg = *(const float4*)(g + col);
    float4 bb4 = *(const float4*)(be + col);
    ushort4 ub;
    ub.x = f2bf((t4.x - mu) * rs * gg.x + bb4.x);
    ub.y = f2bf((t4.y - mu) * rs * gg.y + bb4.y);
    ub.z = f2bf((t4.z - mu) * rs * gg.z + bb4.z);
    ub.w = f2bf((t4.w - mu) * rs * gg.w + bb4.w);
    *(ushort4*)(outb + (size_t)gm * CC + col) = ub;
  }
}

// ================================================================= phases
static __device__ void qv_item(const MP& p, int bid, char* sm) {
  unsigned short* As = (unsigned short*)sm;
  unsigned short* Bs = (unsigned short*)(sm + 8192);
  const unsigned short* Xf0 = p.accbf;
  const unsigned short* Xf1 = p.accbf + 2097152;
  const unsigned short* Xf2 = p.accbf + 3145728;
  if (bid < 256) {
    gemm_ln_q(p.Sbf, p.q_wb, p.q_b, p.Qbf, p.lnq_g, p.lnq_b, bid * 32, sm);
  } else if (bid < 512) {
    int t = bid - 256;
    gemm_body<64, 128, 2, 2, 3>(Xf0, p.vw0b, p.vb0, nullptr, p.V0b, 256, 256,
                                256, 256, 256, nullptr, nullptr,
                                (t >> 1) * 64, (t & 1) * 128, As, Bs);
  } else if (bid < 640) {
    int l = bid - 512, ks = l >> 6, t = l & 63;
    gemm_body<64, 128, 2, 2, 4>(Xf1 + ks * 256, p.vw1b + ks * 256, nullptr,
                                p.Vp1 + (size_t)ks * 524288, nullptr, 256, 256,
                                512, 512, 256, nullptr, nullptr,
                                (t >> 1) * 64, (t & 1) * 128, As, Bs);
  } else {
    int l = bid - 640, ks = l >> 4, t = l & 15;
    gemm_body<64, 128, 2, 2, 4>(Xf2 + ks * 256, p.vw2b + ks * 256, nullptr,
                                p.Vp2 + (size_t)ks * 131072, nullptr, 256, 256,
                                1024, 1024, 256, nullptr, nullptr,
                                (t >> 1) * 64, (t & 1) * 128, As, Bs);
  }
}

static __device__ void offv_item(const MP& p, int bid, char* sm) {
  if (bid < 128) {
    unsigned short* As = (unsigned short*)sm;
    unsigned short* Bs = (unsigned short*)(sm + 8192);
    gemm_body<64, 256, 2, 2, 0>(p.Qbf, p.owb, p.bias144, p.offwgt, nullptr, 144,
                                256, 256, 256, 144, nullptr, nullptr,
                                bid * 64, 0, As, Bs);
  } else if (bid < 640) {
    int e4 = (bid - 128) * 256 + threadIdx.x;
    const float4* P4 = (const float4*)p.Vp1;
    float4 a = P4[e4], b = P4[e4 + 131072];
    float4 bb = *(const float4*)(p.vb1 + ((e4 << 2) & 255));
    ushort4 u;
    u.x = f2bf(a.x + b.x + bb.x); u.y = f2bf(a.y + b.y + bb.y);
    u.z = f2bf(a.z + b.z + bb.z); u.w = f2bf(a.w + b.w + bb.w);
    ((ushort4*)p.V1b)[e4] = u;
  } else {
    int e4 = (bid - 640) * 256 + threadIdx.x;
    const float4* P4 = (const float4*)p.Vp2;
    float4 a = P4[e4], b = P4[e4 + 32768], c = P4[e4 + 65536], d = P4[e4 + 98304];
    float4 bb = *(const float4*)(p.vb2 + ((e4 << 2) & 255));
    ushort4 u;
    u.x = f2bf(a.x + b.x + c.x + d.x + bb.x);
    u.y = f2bf(a.y + b.y + c.y + d.y + bb.y);
    u.z = f2bf(a.z + b.z + c.z + d.z + bb.z);
    u.w = f2bf(a.w + b.w + c.w + d.w + bb.w);
    ((ushort4*)p.V2b)[e4] = u;
  }
}

static __device__ void sample_item(const MP& p, int bn, char* smraw) {
  struct SSh {
    float w[48];
    int xy[48][2];
    float f[48][2];
    uint2 ow2[192];
  };
  SSh& sh = *(SSh*)smraw;
  int q = ((bn & 7) << 10) | (bn >> 3);
  int b = q >> 12, n = q & (NQ - 1);
  int tid = threadIdx.x, head = tid >> 6, lane = tid & 63;
  int half = lane >> 5, l32 = lane & 31;

  __syncthreads();               // guard LDS vs previous iteration readers
  if (tid < 48) {
    int hh = tid / 12, pt = tid % 12, l = pt >> 2, mm = pt & 3;
    int oidx = (hh * 3 + l) * 4 + mm;
    float offx = p.offwgt[(size_t)q * 144 + oidx * 2 + 0];
    float offy = p.offwgt[(size_t)q * 144 + oidx * 2 + 1];
    float refx = ((n & 63) + 0.5f) * (1.f / 64.f);
    float refy = ((n >> 6) + 0.5f) * (1.f / 64.f);
    float gx = tanhf((refx + offx) * 2.f - 1.f);
    float gy = tanhf((refy + offy) * 2.f - 1.f);
    gx = fminf(1.f, fmaxf(-1.f, gx));
    gy = fminf(1.f, fmaxf(-1.f, gy));
    int Wl = 64 >> l;
    float x = (gx + 1.f) * 0.5f * (float)(Wl - 1);
    float y = (gy + 1.f) * 0.5f * (float)(Wl - 1);
    float x0 = floorf(x), y0 = floorf(y);
    sh.xy[tid][0] = (int)x0;
    sh.xy[tid][1] = (int)y0;
    sh.f[tid][0] = x - x0;
    sh.f[tid][1] = y - y0;
    sh.w[tid] = p.offwgt[(size_t)q * 144 + 96 + oidx] * (p.sim[q] + 0.001f);
  }
  __syncthreads();
  if (tid < 4) {
    float mx = -1e30f;
    #pragma unroll
    for (int i = 0; i < 12; i++) mx = fmaxf(mx, sh.w[tid * 12 + i]);
    float e[12], ssum = 0.f;
    #pragma unroll
    for (int i = 0; i < 12; i++) { e[i] = expf(sh.w[tid * 12 + i] - mx); ssum += e[i]; }
    float inv = 1.f / ssum;
    #pragma unroll
    for (int i = 0; i < 12; i++) sh.w[tid * 12 + i] = e[i] * inv;
  }
  __syncthreads();
  if (tid < 192) {
    int s = tid >> 2, tap = tid & 3;
    int l = (s % 12) >> 2;
    int Wl = 64 >> l;
    int X = sh.xy[s][0] + (tap & 1), Y = sh.xy[s][1] + (tap >> 1);
    bool valid = (X >= 0 && X < Wl && Y >= 0 && Y < Wl);
    float wx = (tap & 1) ? sh.f[s][0] : 1.f - sh.f[s][0];
    float wy = (tap >> 1) ? sh.f[s][1] : 1.f - sh.f[s][1];
    float twt = valid ? sh.w[s] * wx * wy : 0.f;
    int Xc = min(max(X, 0), Wl - 1), Yc = min(max(Y, 0), Wl - 1);
    sh.ow2[tid].x = (unsigned)((Yc * Wl + Xc) << 8);
    sh.ow2[tid].y = __float_as_uint(twt);
  }
  __syncthreads();

  const unsigned short* B0 = p.V0b + (size_t)b * 4096 * CC;
  const unsigned short* B1 = p.V1b + (size_t)b * 1024 * CC;
  const unsigned short* B2 = p.V2b + (size_t)b * 256 * CC;
  int ch8 = l32 * 8;
  float a0 = 0.f, a1 = 0.f, a2 = 0.f, a3 = 0.f;
  float a4 = 0.f, a5 = 0.f, a6 = 0.f, a7 = 0.f;
  #pragma unroll
  for (int it = 0; it < 24; it++) {
    const unsigned short* base = (it < 8) ? B0 : (it < 16) ? B1 : B2;
    uint2 owv = sh.ow2[head * 48 + it * 2 + half];
    float w = __uint_as_float(owv.y);
    const uint4 u = *(const uint4*)(base + owv.x + ch8);
    a0 = fmaf(w, __uint_as_float(u.x << 16), a0);
    a1 = fmaf(w, __uint_as_float(u.x & 0xffff0000u), a1);
    a2 = fmaf(w, __uint_as_float(u.y << 16), a2);
    a3 = fmaf(w, __uint_as_float(u.y & 0xffff0000u), a3);
    a4 = fmaf(w, __uint_as_float(u.z << 16), a4);
    a5 = fmaf(w, __uint_as_float(u.z & 0xffff0000u), a5);
    a6 = fmaf(w, __uint_as_float(u.w << 16), a6);
    a7 = fmaf(w, __uint_as_float(u.w & 0xffff0000u), a7);
  }
  a0 += __shfl_xor(a0, 32); a1 += __shfl_xor(a1, 32);
  a2 += __shfl_xor(a2, 32); a3 += __shfl_xor(a3, 32);
  a4 += __shfl_xor(a4, 32); a5 += __shfl_xor(a5, 32);
  a6 += __shfl_xor(a6, 32); a7 += __shfl_xor(a7, 32);
  if (half == 0) {
    uint4 r;
    r.x = (unsigned)f2bf(a0) | ((unsigned)f2bf(a1) << 16);
    r.y = (unsigned)f2bf(a2) | ((unsigned)f2bf(a3) << 16);
    r.z = (unsigned)f2bf(a4) | ((unsigned)f2bf(a5) << 16);
    r.w = (unsigned)f2bf(a6) | ((unsigned)f2bf(a7) << 16);
    *(uint4*)(p.accbf + (size_t)q * 1024 + head * CC + ch8) = r;
  }
}

static __device__ void outA_item(const MP& p, int bid, char* sm) {
  int ks = bid >> 8, m = bid & 255;
  gemm_body<32, 256, 1, 4, 4>(p.accbf + ks * 512, p.out_wb + ks * 512, nullptr,
                              p.Pp + (size_t)ks * 2097152, nullptr, 256, 512,
                              1024, 1024, 256, nullptr, nullptr, m * 32, 0,
                              (unsigned short*)sm, (unsigned short*)(sm + 4096));
}

static __device__ void outB_item(const MP& p, int bid, char* smraw) {
  float (*Ls)[264] = (float(*)[264])smraw;
  int q0 = bid * 16;
  int b = q0 >> 12, qq = q0 & (NQ - 1);
  int t = threadIdx.x;
  {
    int cs = t >> 2, j = (t & 3) * 4;
    #pragma unroll
    for (int c0 = 0; c0 < 256; c0 += 64) {
      float4 sv = *(const float4*)(p.S + (((size_t)(b * 256 + c0 + cs)) << 12) + qq + j);
      Ls[j + 0][c0 + cs] = sv.x; Ls[j + 1][c0 + cs] = sv.y;
      Ls[j + 2][c0 + cs] = sv.z; Ls[j + 3][c0 + cs] = sv.w;
    }
  }
  __syncthreads();
  int c = t;
  float bv = p.out_b[c];
  float val[16];
  #pragma unroll
  for (int r = 0; r < 16; r++) {
    size_t idx = (size_t)(q0 + r) * 256 + c;
    val[r] = p.Pp[idx] + p.Pp[idx + 2097152] + bv + Ls[r][c];
  }
  __syncthreads();
  #pragma unroll
  for (int r = 0; r < 16; r++) Ls[r][c] = val[r];
  __syncthreads();
  int row = t >> 4, lg = t & 15;
  const float* Lr = &Ls[row][lg * 16];
  float s1 = 0.f, s2 = 0.f;
  #pragma unroll
  for (int i = 0; i < 4; i++) {
    float4 t4 = *(const float4*)(Lr + i * 4);
    s1 += t4.x + t4.y + t4.z + t4.w;
    s2 += t4.x * t4.x + t4.y * t4.y + t4.z * t4.z + t4.w * t4.w;
  }
  #pragma unroll
  for (int o = 1; o < 16; o <<= 1) {
    s1 += __shfl_xor(s1, o);
    s2 += __shfl_xor(s2, o);
  }
  float mu = s1 * (1.f / 256.f);
  float var = s2 * (1.f / 256.f) - mu * mu;
  float rs = rsqrtf(var + 1e-5f);
  int gm = q0 + row;
  #pragma unroll
  for (int i = 0; i < 4; i++) {
    int col = lg * 16 + i * 4;
    float4 t4 = *(const float4*)(Lr + i * 4);
    float4 gg = *(const float4*)(p.lno_g + col);
    float4 bb4 = *(const float4*)(p.lno_b + col);
    ushort4 ub;
    ub.x = f2bf((t4.x - mu) * rs * gg.x + bb4.x);
    ub.y = f2bf((t4.y - mu) * rs * gg.y + bb4.y);
    ub.z = f2bf((t4.z - mu) * rs * gg.z + bb4.z);
    ub.w = f2bf((t4.w - mu) * rs * gg.w + bb4.w);
    *(ushort4*)(p.Qbf + (size_t)gm * CC + col) = ub;   // Zbf aliases Qbf
  }
}

static __device__ void fc1_item(const MP& p, int bid, char* sm) {
  int nx = bid & 3, my = bid >> 2;
  gemm_body<64, 256, 2, 2, 1>(p.Qbf, p.fc1_wb, p.fc1_b, nullptr, p.accbf, 1024,
                              256, 256, 256, 1024, nullptr, nullptr,
                              my * 64, nx * 256,
                              (unsigned short*)sm, (unsigned short*)(sm + 8192));
}

static __device__ void fc2_item(const MP& p, int bid, char* sm) {
  int nx = bid & 3, my = bid >> 2;
  gemm_body<64, 64, 2, 2, 2>(p.accbf, p.fc2_wb, p.fc2_b, nullptr, nullptr, 256,
                             1024, 1024, 1024, 256, p.Qbf, p.outp,
                             my * 64, nx * 64,
                             (unsigned short*)sm, (unsigned short*)(sm + 8192));
}

// ================================================================= mega
__global__ __launch_bounds__(256, 3)
void mega_k(MP p) {
  __shared__ __attribute__((aligned(16))) char sm[40960];
  int bid = blockIdx.x;

  for (int w = bid; w < 2944; w += GRID) prep_item(p, w, sm);
  gbar(p.bars, 0);

  if (bid < 704) qv_item(p, bid, sm);
  gbar(p.bars, 1);

  offv_item(p, bid, sm);
  gbar(p.bars, 2);

  for (int w = bid; w < 8192; w += GRID) sample_item(p, w, sm);
  gbar(p.bars, 3);

  if (bid < 512) outA_item(p, bid, sm);
  gbar(p.bars, 4);

  if (bid < 512) outB_item(p, bid, sm);
  gbar(p.bars, 5);

  if (bid < 512) fc1_item(p, bid, sm);
  gbar(p.bars, 6);

  if (bid < 512) fc2_item(p, bid, sm);
}

// ================================================================= launch
extern "C" void kernel_launch(void* const* d_in, const int* in_sizes, int n_in,
                              void* d_out, int out_size, void* d_ws, size_t ws_size,
                              hipStream_t stream) {
  MP p;
  p.S     = (const float*)d_in[0];
  p.f0    = (const float*)d_in[1];
  p.f1    = (const float*)d_in[2];
  p.f2    = (const float*)d_in[3];
  p.sim   = (const float*)d_in[4];
  p.vw0   = (const float*)d_in[5];
  p.vb0   = (const float*)d_in[6];
  p.vw1   = (const float*)d_in[7];
  p.vb1   = (const float*)d_in[8];
  p.vw2   = (const float*)d_in[9];
  p.vb2   = (const float*)d_in[10];
  p.q_w   = (const float*)d_in[11];
  p.q_b   = (const float*)d_in[12];
  p.off_w = (const float*)d_in[13];
  p.off_b = (const float*)d_in[14];
  p.wgt_w = (const float*)d_in[15];
  p.wgt_b = (const float*)d_in[16];
  p.out_w = (const float*)d_in[17];
  p.out_b = (const float*)d_in[18];
  p.lnq_g = (const float*)d_in[19];
  p.lnq_b = (const float*)d_in[20];
  p.lno_g = (const float*)d_in[21];
  p.lno_b = (const float*)d_in[22];
  p.fc1_w = (const float*)d_in[23];
  p.fc1_b = (const float*)d_in[24];
  p.fc2_w = (const float*)d_in[25];
  p.fc2_b = (const float*)d_in[26];

  char* w = (char*)d_ws;
  p.bars    = (unsigned*)w; w += 1024;
  p.offwgt  = (float*)w; w += 4718592;
  p.bias144 = (float*)w; w += 1024;
  p.Pp      = (float*)w; w += 16777216;
  p.Vp1     = (float*)w; w += 4194304;
  p.Vp2     = (float*)w; w += 2097152;
  p.Sbf     = (unsigned short*)w; w += 4194304;
  p.Qbf     = (unsigned short*)w; w += 4194304;    // alias Zbf
  p.accbf   = (unsigned short*)w; w += 16777216;   // alias Xf*, hbf
  p.V0b     = (unsigned short*)w; w += 4194304;
  p.V1b     = (unsigned short*)w; w += 1048576;
  p.V2b     = (unsigned short*)w; w += 262144;
  p.q_wb    = (unsigned short*)w; w += 131072;
  p.owb     = (unsigned short*)w; w += 131072;
  p.vw0b    = (unsigned short*)w; w += 131072;
  p.vw1b    = (unsigned short*)w; w += 262144;
  p.vw2b    = (unsigned short*)w; w += 524288;
  p.out_wb  = (unsigned short*)w; w += 524288;
  p.fc1_wb  = (unsigned short*)w; w += 524288;
  p.fc2_wb  = (unsigned short*)w; w += 524288;
  p.outp    = (float*)d_out;

  hipMemsetAsync(p.bars, 0, 1024, stream);
  mega_k<<<GRID, 256, 0, stream>>>(p);
}

// Round 12
// 265.040 us; speedup vs baseline: 3.6216x; 3.6216x over previous
//
#include <hip/hip_runtime.h>
#include <hip/hip_bf16.h>
#include <math.h>

#define NQ 4096
#define CC 256

typedef __attribute__((ext_vector_type(8))) short bfrag;
typedef __attribute__((ext_vector_type(4))) float ffrag;

__device__ inline unsigned short f2bf(float x) {
  __hip_bfloat16 h = __float2bfloat16(x);
  return *reinterpret_cast<unsigned short*>(&h);
}

__device__ inline float bf2f(unsigned short u) {
  return __uint_as_float(((unsigned)u) << 16);
}

__device__ inline void gload16(const void* g, void* l) {
  __builtin_amdgcn_global_load_lds(
      (const __attribute__((address_space(1))) void*)g,
      (__attribute__((address_space(3))) void*)l, 16, 0, 0);
}

// ================================================================= prep mega
__device__ void tr64(const float* __restrict__ src,
                     unsigned short* __restrict__ dstb, int Cin, int P,
                     int p0, int c0, int b, float (*t)[73]) {
  int tid = threadIdx.x;
  int rx = tid & 15, ry = tid >> 4;
  const float* Sb = src + (size_t)b * Cin * P + p0 + rx * 4;
  #pragma unroll
  for (int i = 0; i < 4; i++) {
    int r = ry + i * 16;
    float4 v = *(const float4*)(Sb + (size_t)(c0 + r) * P);
    t[r][rx * 4 + 0] = v.x; t[r][rx * 4 + 1] = v.y;
    t[r][rx * 4 + 2] = v.z; t[r][rx * 4 + 3] = v.w;
  }
  __syncthreads();
  size_t ob = (size_t)b * P * Cin;
  #pragma unroll
  for (int i = 0; i < 4; i++) {
    int pr = ry + i * 16;
    float x0 = t[rx * 4 + 0][pr], x1 = t[rx * 4 + 1][pr];
    float x2 = t[rx * 4 + 2][pr], x3 = t[rx * 4 + 3][pr];
    size_t idx = ob + (size_t)(p0 + pr) * Cin + c0 + rx * 4;
    ushort4 u4;
    u4.x = f2bf(x0); u4.y = f2bf(x1); u4.z = f2bf(x2); u4.w = f2bf(x3);
    *(ushort4*)(dstb + idx) = u4;
  }
}

__global__ __launch_bounds__(256)
void prep_all_k(const float* S, const float* f0, const float* f1, const float* f2,
                const float* q_w, const float* off_w, const float* wgt_w,
                const float* vw0, const float* vw1, const float* vw2,
                const float* out_w, const float* fc1_w, const float* fc2_w,
                const float* off_b, const float* wgt_b,
                unsigned short* Sbf,
                unsigned short* Xf0, unsigned short* Xf1, unsigned short* Xf2,
                unsigned short* q_wb, unsigned short* owb,
                unsigned short* vw0b, unsigned short* vw1b, unsigned short* vw2b,
                unsigned short* out_wb, unsigned short* fc1_wb,
                unsigned short* fc2_wb, float* bias144) {
  __shared__ float t[64][73];
  int bid = blockIdx.x;
  if (bid < 512) {
    int l = bid;
    tr64(S, Sbf, 256, 4096, (l & 63) * 64, ((l >> 6) & 3) * 64, l >> 8, t);
  } else if (bid < 1024) {
    int l = bid - 512;
    tr64(f0, Xf0, 256, 4096, (l & 63) * 64, ((l >> 6) & 3) * 64, l >> 8, t);
  } else if (bid < 1280) {
    int l = bid - 1024;
    tr64(f1, Xf1, 512, 1024, (l & 15) * 64, ((l >> 4) & 7) * 64, l >> 7, t);
  } else if (bid < 1408) {
    int l = bid - 1280;
    tr64(f2, Xf2, 1024, 256, (l & 3) * 64, ((l >> 2) & 15) * 64, l >> 6, t);
  } else if (bid < 2688) {
    int i4 = (bid - 1408) * 256 + threadIdx.x;
    const float* src; unsigned short* dst;
    if (i4 < 16384)       { src = q_w;   dst = q_wb; }
    else if (i4 < 32768)  { i4 -= 16384;  src = vw0;   dst = vw0b; }
    else if (i4 < 65536)  { i4 -= 32768;  src = vw1;   dst = vw1b; }
    else if (i4 < 131072) { i4 -= 65536;  src = vw2;   dst = vw2b; }
    else if (i4 < 196608) { i4 -= 131072; src = out_w; dst = out_wb; }
    else if (i4 < 262144) { i4 -= 196608; src = fc1_w; dst = fc1_wb; }
    else                  { i4 -= 262144; src = fc2_w; dst = fc2_wb; }
    float4 v = ((const float4*)src)[i4];
    ushort4 u; u.x = f2bf(v.x); u.y = f2bf(v.y); u.z = f2bf(v.z); u.w = f2bf(v.w);
    ((ushort4*)dst)[i4] = u;
  } else {
    int e = (bid - 2688) * 256 + threadIdx.x;
    float v = (e < 24576) ? off_w[e] : (e < 36864 ? wgt_w[e - 24576] : 0.f);
    owb[e] = f2bf(v);
    if (e < 96) bias144[e] = off_b[e];
    else if (e < 144) bias144[e] = wgt_b[e - 96];
  }
}

// ================================================================= GEMM body
// BK=64 k-major LDS. EPI 0: fp32+bias  1: GELU->bf16  2: +bias+bf16 Zres,
// transposed fp32 store  3: bf16+bias  4: fp32 no bias (partial)
template<int BM, int BN, int WM, int WN, int EPI>
__device__ __forceinline__ void gemm_body(
    const unsigned short* __restrict__ A, const unsigned short* __restrict__ B,
    const float* __restrict__ bias, float* __restrict__ outf,
    unsigned short* __restrict__ outb, int N, int Kloop, int lda, int ldb,
    int ldo, const unsigned short* __restrict__ Zres, float* __restrict__ outT,
    int m0, int n0, unsigned short* As, unsigned short* Bs) {
  constexpr int MI = BM / (WM * 16), NI = BN / (WN * 16);
  constexpr int TA = BM / 8, TB = BN / 8;
  constexpr int LBM = (BM == 32) ? 5 : (BM == 64) ? 6 : 7;
  constexpr int LBN = (BN == 64) ? 6 : (BN == 128) ? 7 : 8;
  int tid = threadIdx.x, wave = tid >> 6, lane = tid & 63;
  int quad = lane >> 4, l16 = lane & 15;
  int wm = wave / WN, wn = wave % WN;
  const int mbase = wm * (BM / WM), nbase = wn * (BN / WN);

  ffrag acc[MI][NI];
  #pragma unroll
  for (int i = 0; i < MI; i++)
    #pragma unroll
    for (int j = 0; j < NI; j++) acc[i][j] = (ffrag)0.f;

  for (int k0 = 0; k0 < Kloop; k0 += 64) {
    __syncthreads();
    for (int t = wave; t < TA + TB; t += 4) {
      if (t < TA) {
        int s = t * 64 + lane;
        int kc = s >> LBM, r = s & (BM - 1);
        gload16(A + (size_t)(m0 + r) * lda + k0 + kc * 8, (char*)As + t * 1024);
      } else {
        int s = (t - TA) * 64 + lane;
        int kc = s >> LBN, r = s & (BN - 1);
        gload16(B + (size_t)(n0 + r) * ldb + k0 + kc * 8, (char*)Bs + (t - TA) * 1024);
      }
    }
    __syncthreads();
    #pragma unroll
    for (int ks = 0; ks < 2; ks++) {
      bfrag af[MI], bf[NI];
      #pragma unroll
      for (int mi = 0; mi < MI; mi++)
        af[mi] = *(const bfrag*)(As + ((((ks * 4 + quad) << LBM) + mbase + mi * 16 + l16) << 3));
      #pragma unroll
      for (int ni = 0; ni < NI; ni++)
        bf[ni] = *(const bfrag*)(Bs + ((((ks * 4 + quad) << LBN) + nbase + ni * 16 + l16) << 3));
      #pragma unroll
      for (int mi = 0; mi < MI; mi++)
        #pragma unroll
        for (int ni = 0; ni < NI; ni++)
          acc[mi][ni] = __builtin_amdgcn_mfma_f32_16x16x32_bf16(
              af[mi], bf[ni], acc[mi][ni], 0, 0, 0);
    }
  }

  if (EPI == 2) {
    #pragma unroll
    for (int mi = 0; mi < MI; mi++) {
      int mrow = m0 + mbase + mi * 16 + quad * 4;
      int bb = mrow >> 12, q0 = mrow & (NQ - 1);
      #pragma unroll
      for (int ni = 0; ni < NI; ni++) {
        int n = n0 + nbase + ni * 16 + l16;
        float bv = bias[n];
        float4 v;
        v.x = acc[mi][ni][0] + bv + bf2f(Zres[(size_t)(mrow + 0) * CC + n]);
        v.y = acc[mi][ni][1] + bv + bf2f(Zres[(size_t)(mrow + 1) * CC + n]);
        v.z = acc[mi][ni][2] + bv + bf2f(Zres[(size_t)(mrow + 2) * CC + n]);
        v.w = acc[mi][ni][3] + bv + bf2f(Zres[(size_t)(mrow + 3) * CC + n]);
        *(float4*)(outT + ((size_t)(bb * CC + n)) * NQ + q0) = v;
      }
    }
  } else {
    #pragma unroll
    for (int mi = 0; mi < MI; mi++) {
      int mrow = m0 + mbase + mi * 16 + quad * 4;
      #pragma unroll
      for (int ni = 0; ni < NI; ni++) {
        int n = n0 + nbase + ni * 16 + l16;
        if (n < N) {
          float bv = (EPI == 4) ? 0.f : bias[n];
          #pragma unroll
          for (int r = 0; r < 4; r++) {
            float v = acc[mi][ni][r] + bv;
            if (EPI == 1) {
              v = 0.5f * v * (1.f + erff(v * 0.70710678118654752f));
              outb[(size_t)(mrow + r) * ldo + n] = f2bf(v);
            } else if (EPI == 3) {
              outb[(size_t)(mrow + r) * ldo + n] = f2bf(v);
            } else {
              outf[(size_t)(mrow + r) * ldo + n] = v;
            }
          }
        }
      }
    }
  }
}

// ================================================================= Q GEMM+LN
// BM=32, BN=256, BK=64 (proven config)
__device__ __forceinline__ void gemm_ln_q(
    const unsigned short* __restrict__ A, const unsigned short* __restrict__ B,
    const float* __restrict__ bias, unsigned short* __restrict__ outb,
    const float* __restrict__ g, const float* __restrict__ be,
    int m0, char* sm) {
  unsigned short* As = (unsigned short*)sm;
  unsigned short* Bs = (unsigned short*)(sm + 4096);
  float* L = (float*)sm;
  const int K = 256;

  int tid = threadIdx.x, wave = tid >> 6, lane = tid & 63;
  int quad = lane >> 4, l16 = lane & 15;

  ffrag acc[2][4];
  #pragma unroll
  for (int i = 0; i < 2; i++)
    #pragma unroll
    for (int j = 0; j < 4; j++) acc[i][j] = (ffrag)0.f;

  for (int k0 = 0; k0 < K; k0 += 64) {
    __syncthreads();
    for (int t = wave; t < 36; t += 4) {
      if (t < 4) {
        int s = t * 64 + lane;
        int kc = s >> 5, r = s & 31;
        gload16(A + (size_t)(m0 + r) * K + k0 + kc * 8, sm + t * 1024);
      } else {
        int s = (t - 4) * 64 + lane;
        int kc = s >> 8, r = s & 255;
        gload16(B + (size_t)r * K + k0 + kc * 8, sm + 4096 + (t - 4) * 1024);
      }
    }
    __syncthreads();
    #pragma unroll
    for (int ks = 0; ks < 2; ks++) {
      bfrag af[2], bf[4];
      #pragma unroll
      for (int mi = 0; mi < 2; mi++)
        af[mi] = *(const bfrag*)(As + ((((ks * 4 + quad) << 5) + mi * 16 + l16) << 3));
      #pragma unroll
      for (int ni = 0; ni < 4; ni++)
        bf[ni] = *(const bfrag*)(Bs + ((((ks * 4 + quad) << 8) + wave * 64 + ni * 16 + l16) << 3));
      #pragma unroll
      for (int mi = 0; mi < 2; mi++)
        #pragma unroll
        for (int ni = 0; ni < 4; ni++)
          acc[mi][ni] = __builtin_amdgcn_mfma_f32_16x16x32_bf16(
              af[mi], bf[ni], acc[mi][ni], 0, 0, 0);
    }
  }
  __syncthreads();

  #pragma unroll
  for (int mi = 0; mi < 2; mi++) {
    int row = mi * 16 + quad * 4;
    #pragma unroll
    for (int ni = 0; ni < 4; ni++) {
      int col = wave * 64 + ni * 16 + l16;
      float bv = bias[col];
      #pragma unroll
      for (int r = 0; r < 4; r++)
        L[(row + r) * 264 + col] = acc[mi][ni][r] + bv;
    }
  }
  __syncthreads();

  int row = tid >> 3, j = tid & 7;
  int seg = ((j + row) & 7) * 32;
  const float* Lr = L + row * 264 + seg;
  float s1 = 0.f, s2 = 0.f;
  #pragma unroll
  for (int i = 0; i < 8; i++) {
    float4 t4 = *(const float4*)(Lr + i * 4);
    s1 += t4.x + t4.y + t4.z + t4.w;
    s2 += t4.x * t4.x + t4.y * t4.y + t4.z * t4.z + t4.w * t4.w;
  }
  #pragma unroll
  for (int o = 1; o < 8; o <<= 1) {
    s1 += __shfl_xor(s1, o);
    s2 += __shfl_xor(s2, o);
  }
  float mu = s1 * (1.f / 256.f);
  float var = s2 * (1.f / 256.f) - mu * mu;
  float rs = rsqrtf(var + 1e-5f);
  int gm = m0 + row;
  #pragma unroll
  for (int i = 0; i < 8; i++) {
    int col = seg + i * 4;
    float4 t4 = *(const float4*)(Lr + i * 4);
    float4 gg = *(const float4*)(g + col);
    float4 bb4 = *(const float4*)(be + col);
    ushort4 ub;
    ub.x = f2bf((t4.x - mu) * rs * gg.x + bb4.x);
    ub.y = f2bf((t4.y - mu) * rs * gg.y + bb4.y);
    ub.z = f2bf((t4.z - mu) * rs * gg.z + bb4.z);
    ub.w = f2bf((t4.w - mu) * rs * gg.w + bb4.w);
    *(ushort4*)(outb + (size_t)gm * CC + col) = ub;
  }
}

// ================================================================= kernels
// qv: [0,256) Q-LN | [256,512) V0 | [512,640) V1 split2 | [640,704) V2 split4
__global__ __launch_bounds__(256)
void qv_k(const unsigned short* Sbf, const unsigned short* q_wb, const float* q_b,
          const float* lnq_g, const float* lnq_b, unsigned short* Qbf,
          const unsigned short* Xf0, const unsigned short* Xf1,
          const unsigned short* Xf2, const unsigned short* vw0b,
          const unsigned short* vw1b, const unsigned short* vw2b,
          const float* vb0, unsigned short* V0b, float* Vp1, float* Vp2) {
  __shared__ __attribute__((aligned(16))) char sm[36864];
  int bid = blockIdx.x;
  unsigned short* As = (unsigned short*)sm;
  unsigned short* Bs = (unsigned short*)(sm + 8192);
  if (bid < 256) {
    gemm_ln_q(Sbf, q_wb, q_b, Qbf, lnq_g, lnq_b, bid * 32, sm);
  } else if (bid < 512) {
    int t = bid - 256;
    gemm_body<64, 128, 2, 2, 3>(Xf0, vw0b, vb0, nullptr, V0b, 256, 256, 256, 256,
                                256, nullptr, nullptr, (t >> 1) * 64, (t & 1) * 128, As, Bs);
  } else if (bid < 640) {
    int l = bid - 512, ks = l >> 6, t = l & 63;
    gemm_body<64, 128, 2, 2, 4>(Xf1 + ks * 256, vw1b + ks * 256, nullptr,
                                Vp1 + (size_t)ks * 524288, nullptr, 256, 256, 512, 512,
                                256, nullptr, nullptr, (t >> 1) * 64, (t & 1) * 128, As, Bs);
  } else {
    int l = bid - 640, ks = l >> 4, t = l & 15;
    gemm_body<64, 128, 2, 2, 4>(Xf2 + ks * 256, vw2b + ks * 256, nullptr,
                                Vp2 + (size_t)ks * 131072, nullptr, 256, 256, 1024, 1024,
                                256, nullptr, nullptr, (t >> 1) * 64, (t & 1) * 128, As, Bs);
  }
}

// offv: [0,128) offwgt GEMM (BN=256, 1 n-tile) | [128,640) V1 red | [640,768) V2 red
__global__ __launch_bounds__(256)
void offv_k(const unsigned short* Qbf, const unsigned short* owb,
            const float* bias144, float* offwgt,
            const float* Vp1, const float* Vp2, const float* vb1,
            const float* vb2, unsigned short* V1b, unsigned short* V2b) {
  __shared__ __attribute__((aligned(16))) unsigned short As[4096];
  __shared__ __attribute__((aligned(16))) unsigned short Bs[16384];
  int bid = blockIdx.x;
  if (bid < 128) {
    gemm_body<64, 256, 2, 2, 0>(Qbf, owb, bias144, offwgt, nullptr, 144, 256, 256,
                                256, 144, nullptr, nullptr, bid * 64, 0, As, Bs);
  } else if (bid < 640) {
    int e4 = (bid - 128) * 256 + threadIdx.x;
    const float4* P = (const float4*)Vp1;
    float4 a = P[e4], b = P[e4 + 131072];
    float4 bb = *(const float4*)(vb1 + ((e4 << 2) & 255));
    ushort4 u;
    u.x = f2bf(a.x + b.x + bb.x); u.y = f2bf(a.y + b.y + bb.y);
    u.z = f2bf(a.z + b.z + bb.z); u.w = f2bf(a.w + b.w + bb.w);
    ((ushort4*)V1b)[e4] = u;
  } else {
    int e4 = (bid - 640) * 256 + threadIdx.x;
    const float4* P = (const float4*)Vp2;
    float4 a = P[e4], b = P[e4 + 32768], c = P[e4 + 65536], d = P[e4 + 98304];
    float4 bb = *(const float4*)(vb2 + ((e4 << 2) & 255));
    ushort4 u;
    u.x = f2bf(a.x + b.x + c.x + d.x + bb.x);
    u.y = f2bf(a.y + b.y + c.y + d.y + bb.y);
    u.z = f2bf(a.z + b.z + c.z + d.z + bb.z);
    u.w = f2bf(a.w + b.w + c.w + d.w + bb.w);
    ((ushort4*)V2b)[e4] = u;
  }
}

// outA: split-K=2 GEMM acc@out_w -> fp32 partials [2][8192][256]
__global__ __launch_bounds__(256)
void outA_k(const unsigned short* accbf, const unsigned short* out_wb, float* Op) {
  __shared__ __attribute__((aligned(16))) char sm[36864];
  int ks = blockIdx.y;
  gemm_body<32, 256, 1, 4, 4>(accbf + ks * 512, out_wb + ks * 512, nullptr,
                              Op + (size_t)ks * 2097152, nullptr, 256, 512,
                              1024, 1024, 256, nullptr, nullptr, blockIdx.x * 32, 0,
                              (unsigned short*)sm, (unsigned short*)(sm + 4096));
}

// outB: reduce 2 partials + bias + S residual + LN -> Zbf bf16
__global__ __launch_bounds__(256)
void outB_k(const float* __restrict__ Op, const float* __restrict__ S,
            const float* __restrict__ out_b, const float* __restrict__ g,
            const float* __restrict__ be, unsigned short* __restrict__ Zbf) {
  __shared__ float Ls[16][264];
  int q0 = blockIdx.x * 16;
  int b = q0 >> 12, qq = q0 & (NQ - 1);
  int t = threadIdx.x;
  {
    int cs = t >> 2, j = (t & 3) * 4;
    #pragma unroll
    for (int c0 = 0; c0 < 256; c0 += 64) {
      float4 sv = *(const float4*)(S + (((size_t)(b * 256 + c0 + cs)) << 12) + qq + j);
      Ls[j + 0][c0 + cs] = sv.x; Ls[j + 1][c0 + cs] = sv.y;
      Ls[j + 2][c0 + cs] = sv.z; Ls[j + 3][c0 + cs] = sv.w;
    }
  }
  __syncthreads();
  int c = t;
  float bv = out_b[c];
  float val[16];
  #pragma unroll
  for (int r = 0; r < 16; r++) {
    size_t idx = (size_t)(q0 + r) * 256 + c;
    val[r] = Op[idx] + Op[idx + 2097152] + bv + Ls[r][c];
  }
  __syncthreads();
  #pragma unroll
  for (int r = 0; r < 16; r++) Ls[r][c] = val[r];
  __syncthreads();
  int row = t >> 4, lg = t & 15;
  const float* Lr = &Ls[row][lg * 16];
  float s1 = 0.f, s2 = 0.f;
  #pragma unroll
  for (int i = 0; i < 4; i++) {
    float4 t4 = *(const float4*)(Lr + i * 4);
    s1 += t4.x + t4.y + t4.z + t4.w;
    s2 += t4.x * t4.x + t4.y * t4.y + t4.z * t4.z + t4.w * t4.w;
  }
  #pragma unroll
  for (int o = 1; o < 16; o <<= 1) {
    s1 += __shfl_xor(s1, o);
    s2 += __shfl_xor(s2, o);
  }
  float mu = s1 * (1.f / 256.f);
  float var = s2 * (1.f / 256.f) - mu * mu;
  float rs = rsqrtf(var + 1e-5f);
  int gm = q0 + row;
  #pragma unroll
  for (int i = 0; i < 4; i++) {
    int col = lg * 16 + i * 4;
    float4 t4 = *(const float4*)(Lr + i * 4);
    float4 gg = *(const float4*)(g + col);
    float4 bb4 = *(const float4*)(be + col);
    ushort4 ub;
    ub.x = f2bf((t4.x - mu) * rs * gg.x + bb4.x);
    ub.y = f2bf((t4.y - mu) * rs * gg.y + bb4.y);
    ub.z = f2bf((t4.z - mu) * rs * gg.z + bb4.z);
    ub.w = f2bf((t4.w - mu) * rs * gg.w + bb4.w);
    *(ushort4*)(Zbf + (size_t)gm * CC + col) = ub;
  }
}

// fc1: 64x256 tile -> grid (4,128)
__global__ __launch_bounds__(256)
void fc1_k(const unsigned short* Zbf, const unsigned short* fc1_wb,
           const float* fc1_b, unsigned short* hbf) {
  __shared__ __attribute__((aligned(16))) unsigned short As[4096];
  __shared__ __attribute__((aligned(16))) unsigned short Bs[16384];
  gemm_body<64, 256, 2, 2, 1>(Zbf, fc1_wb, fc1_b, nullptr, hbf, 1024, 256, 256,
                              256, 1024, nullptr, nullptr,
                              blockIdx.y * 64, blockIdx.x * 256, As, Bs);
}

// fc2: fused full-K=1024, 64x64 tile, EPI=2 with bf16 Z residual
__global__ __launch_bounds__(256)
void fc2_k(const unsigned short* hbf, const unsigned short* fc2_wb,
           const float* fc2_b, const unsigned short* Zbf, float* outp) {
  __shared__ __attribute__((aligned(16))) unsigned short As[4096];
  __shared__ __attribute__((aligned(16))) unsigned short Bs[4096];
  gemm_body<64, 64, 2, 2, 2>(hbf, fc2_wb, fc2_b, nullptr, nullptr, 256, 1024,
                             1024, 1024, 256, Zbf, outp,
                             blockIdx.y * 64, blockIdx.x * 64, As, Bs);
}

// ================================================================= sampling
__global__ __launch_bounds__(256)
void sample_k(const float* __restrict__ ow, const float* __restrict__ sim,
              const unsigned short* __restrict__ V0, const unsigned short* __restrict__ V1,
              const unsigned short* __restrict__ V2, unsigned short* __restrict__ acc) {
  int bn = blockIdx.x;
  int q = ((bn & 7) << 10) | (bn >> 3);
  int b = q >> 12, n = q & (NQ - 1);
  int tid = threadIdx.x, head = tid >> 6, lane = tid & 63;
  int half = lane >> 5, l32 = lane & 31;

  __shared__ float s_w[48];
  __shared__ int   s_xy[48][2];
  __shared__ float s_f[48][2];
  __shared__ uint2 s_ow[192];

  if (tid < 48) {
    int hh = tid / 12, pt = tid % 12, l = pt >> 2, mm = pt & 3;
    int oidx = (hh * 3 + l) * 4 + mm;
    float offx = ow[(size_t)q * 144 + oidx * 2 + 0];
    float offy = ow[(size_t)q * 144 + oidx * 2 + 1];
    float refx = ((n & 63) + 0.5f) * (1.f / 64.f);
    float refy = ((n >> 6) + 0.5f) * (1.f / 64.f);
    float gx = tanhf((refx + offx) * 2.f - 1.f);
    float gy = tanhf((refy + offy) * 2.f - 1.f);
    gx = fminf(1.f, fmaxf(-1.f, gx));
    gy = fminf(1.f, fmaxf(-1.f, gy));
    int Wl = 64 >> l;
    float x = (gx + 1.f) * 0.5f * (float)(Wl - 1);
    float y = (gy + 1.f) * 0.5f * (float)(Wl - 1);
    float x0 = floorf(x), y0 = floorf(y);
    s_xy[tid][0] = (int)x0;
    s_xy[tid][1] = (int)y0;
    s_f[tid][0] = x - x0;
    s_f[tid][1] = y - y0;
    s_w[tid] = ow[(size_t)q * 144 + 96 + oidx] * (sim[q] + 0.001f);
  }
  __syncthreads();
  if (tid < 4) {
    float mx = -1e30f;
    #pragma unroll
    for (int i = 0; i < 12; i++) mx = fmaxf(mx, s_w[tid * 12 + i]);
    float e[12], ssum = 0.f;
    #pragma unroll
    for (int i = 0; i < 12; i++) { e[i] = expf(s_w[tid * 12 + i] - mx); ssum += e[i]; }
    float inv = 1.f / ssum;
    #pragma unroll
    for (int i = 0; i < 12; i++) s_w[tid * 12 + i] = e[i] * inv;
  }
  __syncthreads();
  if (tid < 192) {
    int s = tid >> 2, tap = tid & 3;
    int l = (s % 12) >> 2;
    int Wl = 64 >> l;
    int X = s_xy[s][0] + (tap & 1), Y = s_xy[s][1] + (tap >> 1);
    bool valid = (X >= 0 && X < Wl && Y >= 0 && Y < Wl);
    float wx = (tap & 1) ? s_f[s][0] : 1.f - s_f[s][0];
    float wy = (tap >> 1) ? s_f[s][1] : 1.f - s_f[s][1];
    float twt = valid ? s_w[s] * wx * wy : 0.f;
    int Xc = min(max(X, 0), Wl - 1), Yc = min(max(Y, 0), Wl - 1);
    s_ow[tid].x = (unsigned)((Yc * Wl + Xc) << 8);
    s_ow[tid].y = __float_as_uint(twt);
  }
  __syncthreads();

  const unsigned short* B0 = V0 + (size_t)b * 4096 * CC;
  const unsigned short* B1 = V1 + (size_t)b * 1024 * CC;
  const unsigned short* B2 = V2 + (size_t)b * 256 * CC;
  int ch8 = l32 * 8;
  float a0 = 0.f, a1 = 0.f, a2 = 0.f, a3 = 0.f;
  float a4 = 0.f, a5 = 0.f, a6 = 0.f, a7 = 0.f;
  #pragma unroll
  for (int it = 0; it < 24; it++) {
    const unsigned short* base = (it < 8) ? B0 : (it < 16) ? B1 : B2;
    uint2 owv = s_ow[head * 48 + it * 2 + half];
    float w = __uint_as_float(owv.y);
    const uint4 u = *(const uint4*)(base + owv.x + ch8);
    a0 = fmaf(w, __uint_as_float(u.x << 16), a0);
    a1 = fmaf(w, __uint_as_float(u.x & 0xffff0000u), a1);
    a2 = fmaf(w, __uint_as_float(u.y << 16), a2);
    a3 = fmaf(w, __uint_as_float(u.y & 0xffff0000u), a3);
    a4 = fmaf(w, __uint_as_float(u.z << 16), a4);
    a5 = fmaf(w, __uint_as_float(u.z & 0xffff0000u), a5);
    a6 = fmaf(w, __uint_as_float(u.w << 16), a6);
    a7 = fmaf(w, __uint_as_float(u.w & 0xffff0000u), a7);
  }
  a0 += __shfl_xor(a0, 32); a1 += __shfl_xor(a1, 32);
  a2 += __shfl_xor(a2, 32); a3 += __shfl_xor(a3, 32);
  a4 += __shfl_xor(a4, 32); a5 += __shfl_xor(a5, 32);
  a6 += __shfl_xor(a6, 32); a7 += __shfl_xor(a7, 32);
  if (half == 0) {
    uint4 r;
    r.x = (unsigned)f2bf(a0) | ((unsigned)f2bf(a1) << 16);
    r.y = (unsigned)f2bf(a2) | ((unsigned)f2bf(a3) << 16);
    r.z = (unsigned)f2bf(a4) | ((unsigned)f2bf(a5) << 16);
    r.w = (unsigned)f2bf(a6) | ((unsigned)f2bf(a7) << 16);
    *(uint4*)(acc + (size_t)q * 1024 + head * CC + ch8) = r;
  }
}

// ================================================================= launch
extern "C" void kernel_launch(void* const* d_in, const int* in_sizes, int n_in,
                              void* d_out, int out_size, void* d_ws, size_t ws_size,
                              hipStream_t stream) {
  const float* S     = (const float*)d_in[0];
  const float* f0    = (const float*)d_in[1];
  const float* f1    = (const float*)d_in[2];
  const float* f2    = (const float*)d_in[3];
  const float* sim   = (const float*)d_in[4];
  const float* vw0   = (const float*)d_in[5];
  const float* vb0   = (const float*)d_in[6];
  const float* vw1   = (const float*)d_in[7];
  const float* vb1   = (const float*)d_in[8];
  const float* vw2   = (const float*)d_in[9];
  const float* vb2   = (const float*)d_in[10];
  const float* q_w   = (const float*)d_in[11];
  const float* q_b   = (const float*)d_in[12];
  const float* off_w = (const float*)d_in[13];
  const float* off_b = (const float*)d_in[14];
  const float* wgt_w = (const float*)d_in[15];
  const float* wgt_b = (const float*)d_in[16];
  const float* out_w = (const float*)d_in[17];
  const float* out_b = (const float*)d_in[18];
  const float* lnq_g = (const float*)d_in[19];
  const float* lnq_b = (const float*)d_in[20];
  const float* lno_g = (const float*)d_in[21];
  const float* lno_b = (const float*)d_in[22];
  const float* fc1_w = (const float*)d_in[23];
  const float* fc1_b = (const float*)d_in[24];
  const float* fc2_w = (const float*)d_in[25];
  const float* fc2_b = (const float*)d_in[26];

  char* p = (char*)d_ws;
  float* offwgt = (float*)p; p += 4718592;
  float* bias144 = (float*)p; p += 1024;
  float* Pp     = (float*)p; p += 16777216;   // outA partials (2 slices)
  float* Vp1    = (float*)p; p += 4194304;
  float* Vp2    = (float*)p; p += 2097152;
  unsigned short* Sbf   = (unsigned short*)p; p += 4194304;
  unsigned short* Qbf   = (unsigned short*)p; p += 4194304;   // alias Zbf
  unsigned short* accbf = (unsigned short*)p; p += 16777216;  // alias Xf*, hbf
  unsigned short* V0b   = (unsigned short*)p; p += 4194304;
  unsigned short* V1b   = (unsigned short*)p; p += 1048576;
  unsigned short* V2b   = (unsigned short*)p; p += 262144;
  unsigned short* q_wb   = (unsigned short*)p; p += 131072;
  unsigned short* owb    = (unsigned short*)p; p += 131072;
  unsigned short* vw0b   = (unsigned short*)p; p += 131072;
  unsigned short* vw1b   = (unsigned short*)p; p += 262144;
  unsigned short* vw2b   = (unsigned short*)p; p += 524288;
  unsigned short* out_wb = (unsigned short*)p; p += 524288;
  unsigned short* fc1_wb = (unsigned short*)p; p += 524288;
  unsigned short* fc2_wb = (unsigned short*)p; p += 524288;

  unsigned short* Xf0 = accbf;
  unsigned short* Xf1 = accbf + 2097152;
  unsigned short* Xf2 = accbf + 3145728;
  unsigned short* Zbf = Qbf;
  unsigned short* hbf = accbf;
  float* outp = (float*)d_out;

  prep_all_k<<<2944, 256, 0, stream>>>(S, f0, f1, f2, q_w, off_w, wgt_w,
      vw0, vw1, vw2, out_w, fc1_w, fc2_w, off_b, wgt_b,
      Sbf, Xf0, Xf1, Xf2, q_wb, owb, vw0b, vw1b, vw2b, out_wb,
      fc1_wb, fc2_wb, bias144);

  qv_k<<<704, 256, 0, stream>>>(Sbf, q_wb, q_b, lnq_g, lnq_b, Qbf,
      Xf0, Xf1, Xf2, vw0b, vw1b, vw2b, vb0, V0b, Vp1, Vp2);

  offv_k<<<768, 256, 0, stream>>>(Qbf, owb, bias144, offwgt,
      Vp1, Vp2, vb1, vb2, V1b, V2b);

  sample_k<<<8192, 256, 0, stream>>>(offwgt, sim, V0b, V1b, V2b, accbf);

  outA_k<<<dim3(256, 2), 256, 0, stream>>>(accbf, out_wb, Pp);

  outB_k<<<512, 256, 0, stream>>>(Pp, S, out_b, lno_g, lno_b, Zbf);

  fc1_k<<<dim3(4, 128), 256, 0, stream>>>(Zbf, fc1_wb, fc1_b, hbf);

  fc2_k<<<dim3(4, 128), 256, 0, stream>>>(hbf, fc2_wb, fc2_b, Zbf, outp);
}